// Round 2
// baseline (315.995 us; speedup 1.0000x reference)
//
#include <hip/hip_runtime.h>
#include <stdint.h>

#define NROWS 8192
#define MCOLS 8192
#define KDIM  256

typedef __bf16 bf16x8 __attribute__((ext_vector_type(8)));
typedef float  floatx4 __attribute__((ext_vector_type(4)));

__device__ __forceinline__ unsigned short f32_to_bf16_rne(float f) {
    unsigned int u = __float_as_uint(f);
    u += 0x7FFFu + ((u >> 16) & 1u);   // round-to-nearest-even
    return (unsigned short)(u >> 16);
}
__device__ __forceinline__ float bf16_to_f32(unsigned short h) {
    return __uint_as_float(((unsigned int)h) << 16);
}

// async 16B global -> LDS (wave-uniform base + lane*16 pattern required)
__device__ __forceinline__ void async16(const void* g, void* l) {
    __builtin_amdgcn_global_load_lds(
        (const __attribute__((address_space(1))) unsigned int*)g,
        (__attribute__((address_space(3))) unsigned int*)l,
        16, 0, 0);
}

// ---------------- kernel 1: alpha = softmax(alpha_raw^2), sa = sqrt(alpha) ----
// wave-level shuffle reductions; 3 barriers instead of 16.
__global__ void prep_alpha(const float* __restrict__ araw, float* __restrict__ sa) {
    int d = threadIdx.x;
    float z = araw[d];
    z = z * z;
    float m = z;
#pragma unroll
    for (int off = 32; off; off >>= 1) m = fmaxf(m, __shfl_xor(m, off));
    __shared__ float wred[4];
    if ((d & 63) == 0) wred[d >> 6] = m;
    __syncthreads();
    float mx = fmaxf(fmaxf(wred[0], wred[1]), fmaxf(wred[2], wred[3]));
    float e = __expf(z - mx);
    float s = e;
#pragma unroll
    for (int off = 32; off; off >>= 1) s += __shfl_xor(s, off);
    __syncthreads();                 // all reads of wred (max) done before reuse
    if ((d & 63) == 0) wred[d >> 6] = s;
    __syncthreads();
    float sum = wred[0] + wred[1] + wred[2] + wred[3];
    sa[d] = sqrtf(e / sum);
}

// ---------------- kernel 2: scale rows by sa, round to bf16, norms from rounded
// merged A and B prep into one launch; shuffle reduction (1 barrier).
__global__ void prep_rows(const float* __restrict__ x1, const float* __restrict__ x2,
                          const float* __restrict__ sa,
                          unsigned short* __restrict__ Amat, unsigned short* __restrict__ Bmat,
                          float* __restrict__ ra, float* __restrict__ rb) {
    int blk = blockIdx.x;
    const float* x; unsigned short* mat; float* nrm; int row;
    if (blk < NROWS) { x = x1; mat = Amat; nrm = ra; row = blk; }
    else             { x = x2; mat = Bmat; nrm = rb; row = blk - NROWS; }
    int d = threadIdx.x;
    float v = x[(size_t)row * KDIM + d] * sa[d];
    unsigned short h = f32_to_bf16_rne(v);
    mat[(size_t)row * KDIM + d] = h;
    float fv = bf16_to_f32(h);
    float p = fv * fv;
#pragma unroll
    for (int off = 32; off; off >>= 1) p += __shfl_xor(p, off);
    __shared__ float wred[4];
    if ((d & 63) == 0) wred[d >> 6] = p;
    __syncthreads();
    if (d == 0) nrm[row] = wred[0] + wred[1] + wred[2] + wred[3];
}

// ---------------- kernel 3: NT-GEMM + fused RBF epilogue ---------------------
// C[i,j] = sum_k A[i,k]*B[j,k];  out = var*exp(-0.5*max(ra_i - 2C + rb_j, 0))
// Tile 128x128, BK=64, 4 waves (2x2), each wave 64x64 via 4x4 of 16x16x32 MFMA.
// LDS tiles stored as 16B chunks, slot = row*8 + (kchunk ^ (row&7))  (XOR swizzle:
// keeps global_load_lds lane-consecutive AND makes ds_read_b128 conflict-free).
// v2 (resubmit; prior round was an infra failure, no measurement):
//   double-buffered LDS with prefetch-before-compute (T3-min 2-phase),
//   XCD-slab block swizzle (3 MiB A+B panel set per XCD L2), NT output stores.
__global__ __launch_bounds__(256) void rbf_gemm(
    const unsigned short* __restrict__ A, const unsigned short* __restrict__ B,
    const float* __restrict__ ra, const float* __restrict__ rb,
    const float* __restrict__ vraw, float* __restrict__ out)
{
    __shared__ unsigned short As[2][128 * 64];   // 2 x 16 KiB
    __shared__ unsigned short Bs[2][128 * 64];   // 2 x 16 KiB  (total 64 KiB)

    const int tid  = threadIdx.x;
    const int lane = tid & 63;
    const int wave = tid >> 6;

    // XCD-slab swizzle: 8 XCDs, each owns a 32(bm) x 16(bn) region of the 64x64
    // grid -> per-XCD working set = (32+16) panels * 64 KiB = 3 MiB < 4 MiB L2.
    // nwg = 4096, divisible by 8 -> bijective.
    const int g   = blockIdx.y * gridDim.x + blockIdx.x;
    const int xcd = g & 7;
    const int i   = g >> 3;                      // 0..511 within slab
    const int bm  = (xcd >> 2) * 32 + (i >> 4);  // row block (x1)
    const int bn  = (xcd & 3) * 16 + (i & 15);   // col block (x2)

    const int wm = (wave & 1) * 64;
    const int wn = (wave >> 1) * 64;
    const int quad = lane >> 4;
    const int l15  = lane & 15;

    floatx4 acc[4][4];
#pragma unroll
    for (int ti = 0; ti < 4; ti++)
#pragma unroll
        for (int tj = 0; tj < 4; tj++) acc[ti][tj] = (floatx4)0.0f;

    auto stage = [&](int buf, int k0) {
#pragma unroll
        for (int it = 0; it < 4; ++it) {
            int c   = it * 256 + tid;      // 16B chunk index 0..1023
            int row = c >> 3;              // tile row 0..127
            int kc  = c & 7;               // chunk-of-8-bf16 within BK=64
            int gkc = kc ^ (row & 7);      // XOR swizzle on the global side
            const unsigned short* gA = A + (size_t)(bm * 128 + row) * KDIM + k0 + gkc * 8;
            const unsigned short* gB = B + (size_t)(bn * 128 + row) * KDIM + k0 + gkc * 8;
            async16(gA, &As[buf][c * 8]);
            async16(gB, &Bs[buf][c * 8]);
        }
    };

    stage(0, 0);
    __syncthreads();                       // vmcnt(0) drain of prologue stage

#pragma unroll
    for (int t = 0; t < 4; ++t) {
        if (t < 3) stage((t + 1) & 1, (t + 1) * 64);   // prefetch next K-tile
        const unsigned short* Ab = As[t & 1];
        const unsigned short* Bb = Bs[t & 1];
#pragma unroll
        for (int ks = 0; ks < 2; ++ks) {
            bf16x8 af[4], bfr[4];
            int kc = ks * 4 + quad;        // k = ks*32 + quad*8 -> chunk index
#pragma unroll
            for (int tt = 0; tt < 4; ++tt) {
                int m   = wm + tt * 16 + l15;
                int sA  = m * 8 + (kc ^ (m & 7));
                af[tt]  = *(const bf16x8*)&Ab[sA * 8];
                int n   = wn + tt * 16 + l15;
                int sB  = n * 8 + (kc ^ (n & 7));
                bfr[tt] = *(const bf16x8*)&Bb[sB * 8];
            }
#pragma unroll
            for (int ti = 0; ti < 4; ++ti)
#pragma unroll
                for (int tj = 0; tj < 4; ++tj)
                    acc[ti][tj] = __builtin_amdgcn_mfma_f32_16x16x32_bf16(
                        af[ti], bfr[tj], acc[ti][tj], 0, 0, 0);
        }
        if (t < 3) __syncthreads();        // prefetched tile now resident
    }

    // epilogue: C/D layout col = lane&15, row = quad*4 + reg
    float variance = vraw[0] * vraw[0];
    float rbv[4];
#pragma unroll
    for (int tj = 0; tj < 4; ++tj) rbv[tj] = rb[bn * 128 + wn + tj * 16 + l15];
#pragma unroll
    for (int ti = 0; ti < 4; ++ti) {
        int rowbase = bm * 128 + wm + ti * 16 + quad * 4;
        float rav[4];
#pragma unroll
        for (int r = 0; r < 4; ++r) rav[r] = ra[rowbase + r];
#pragma unroll
        for (int tj = 0; tj < 4; ++tj) {
            int col = bn * 128 + wn + tj * 16 + l15;
#pragma unroll
            for (int r = 0; r < 4; ++r) {
                float s = rav[r] + rbv[tj] - 2.0f * acc[ti][tj][r];
                s = fmaxf(s, 0.0f);
                float val = variance * __expf(-0.5f * s);
                // out is never re-read: stream past L2, keep A/B panels resident
                __builtin_nontemporal_store(val, &out[(size_t)(rowbase + r) * MCOLS + col]);
            }
        }
    }
}

extern "C" void kernel_launch(void* const* d_in, const int* in_sizes, int n_in,
                              void* d_out, int out_size, void* d_ws, size_t ws_size,
                              hipStream_t stream) {
    const float* x1   = (const float*)d_in[0];
    const float* x2   = (const float*)d_in[1];
    const float* araw = (const float*)d_in[2];
    const float* vraw = (const float*)d_in[3];
    float* out = (float*)d_out;

    char* ws = (char*)d_ws;
    float* sa = (float*)ws;                               // 256 f32   @ 0
    float* ra = (float*)(ws + 1024);                      // 8192 f32  @ 1 KiB
    float* rb = (float*)(ws + 1024 + 32768);              // 8192 f32
    unsigned short* Amat = (unsigned short*)(ws + 66560);                            // 4 MiB bf16
    unsigned short* Bmat = (unsigned short*)(ws + 66560 + (size_t)NROWS * KDIM * 2); // 4 MiB bf16

    prep_alpha<<<1, 256, 0, stream>>>(araw, sa);
    prep_rows<<<NROWS + MCOLS, 256, 0, stream>>>(x1, x2, sa, Amat, Bmat, ra, rb);

    dim3 grid(MCOLS / 128, NROWS / 128);
    rbf_gemm<<<grid, 256, 0, stream>>>(Amat, Bmat, ra, rb, vraw, out);
}

// Round 3
// 313.007 us; speedup vs baseline: 1.0095x; 1.0095x over previous
//
#include <hip/hip_runtime.h>
#include <stdint.h>

#define NROWS 8192
#define MCOLS 8192
#define KDIM  256

typedef __bf16 bf16x8 __attribute__((ext_vector_type(8)));
typedef float  floatx4 __attribute__((ext_vector_type(4)));

__device__ __forceinline__ unsigned short f32_to_bf16_rne(float f) {
    unsigned int u = __float_as_uint(f);
    u += 0x7FFFu + ((u >> 16) & 1u);   // round-to-nearest-even
    return (unsigned short)(u >> 16);
}
__device__ __forceinline__ float bf16_to_f32(unsigned short h) {
    return __uint_as_float(((unsigned int)h) << 16);
}

// async 16B global -> LDS (wave-uniform base + lane*16 pattern required)
__device__ __forceinline__ void async16(const void* g, void* l) {
    __builtin_amdgcn_global_load_lds(
        (const __attribute__((address_space(1))) unsigned int*)g,
        (__attribute__((address_space(3))) unsigned int*)l,
        16, 0, 0);
}

// ---------------- kernel 1: alpha = softmax(alpha_raw^2), sa = sqrt(alpha) ----
__global__ void prep_alpha(const float* __restrict__ araw, float* __restrict__ sa) {
    int d = threadIdx.x;
    float z = araw[d];
    z = z * z;
    float m = z;
#pragma unroll
    for (int off = 32; off; off >>= 1) m = fmaxf(m, __shfl_xor(m, off));
    __shared__ float wred[4];
    if ((d & 63) == 0) wred[d >> 6] = m;
    __syncthreads();
    float mx = fmaxf(fmaxf(wred[0], wred[1]), fmaxf(wred[2], wred[3]));
    float e = __expf(z - mx);
    float s = e;
#pragma unroll
    for (int off = 32; off; off >>= 1) s += __shfl_xor(s, off);
    __syncthreads();
    if ((d & 63) == 0) wred[d >> 6] = s;
    __syncthreads();
    float sum = wred[0] + wred[1] + wred[2] + wred[3];
    sa[d] = sqrtf(e / sum);
}

// ---------------- kernel 2: scale rows by sa, round to bf16, norms from rounded
__global__ void prep_rows(const float* __restrict__ x1, const float* __restrict__ x2,
                          const float* __restrict__ sa,
                          unsigned short* __restrict__ Amat, unsigned short* __restrict__ Bmat,
                          float* __restrict__ ra, float* __restrict__ rb) {
    int blk = blockIdx.x;
    const float* x; unsigned short* mat; float* nrm; int row;
    if (blk < NROWS) { x = x1; mat = Amat; nrm = ra; row = blk; }
    else             { x = x2; mat = Bmat; nrm = rb; row = blk - NROWS; }
    int d = threadIdx.x;
    float v = x[(size_t)row * KDIM + d] * sa[d];
    unsigned short h = f32_to_bf16_rne(v);
    mat[(size_t)row * KDIM + d] = h;
    float fv = bf16_to_f32(h);
    float p = fv * fv;
#pragma unroll
    for (int off = 32; off; off >>= 1) p += __shfl_xor(p, off);
    __shared__ float wred[4];
    if ((d & 63) == 0) wred[d >> 6] = p;
    __syncthreads();
    if (d == 0) nrm[row] = wred[0] + wred[1] + wred[2] + wred[3];
}

// ---------------- kernel 3: NT-GEMM + fused RBF epilogue ---------------------
// C[i,j] = sum_k A[i,k]*B[j,k];  out = var*exp(-0.5*max(ra_i - 2C + rb_j, 0))
// Tile 128x128, BK=64, 4 waves (2x2), each wave 64x64 via 4x4 of 16x16x32 MFMA.
// v3: WRITE-BOUND analysis (write roofline 43 us; MFMA only ~4 us).
//   - TRANSPOSED accumulator: mfma(bfr, af) -> lane holds 4 consecutive output
//     COLUMNS per fragment -> global_store_dwordx4 (16 stores/thread, was 64).
//   - reverted nontemporal stores (v2 regression suspect: bypassing L2 defeats
//     write-combining of the 64 B quad segments into full lines).
//   - kept: double-buffered LDS prefetch, XCD-slab swizzle, XOR LDS swizzle.
__global__ __launch_bounds__(256) void rbf_gemm(
    const unsigned short* __restrict__ A, const unsigned short* __restrict__ B,
    const float* __restrict__ ra, const float* __restrict__ rb,
    const float* __restrict__ vraw, float* __restrict__ out)
{
    __shared__ unsigned short As[2][128 * 64];   // 2 x 16 KiB
    __shared__ unsigned short Bs[2][128 * 64];   // 2 x 16 KiB  (total 64 KiB)

    const int tid  = threadIdx.x;
    const int lane = tid & 63;
    const int wave = tid >> 6;

    // XCD-slab swizzle: each XCD owns a 32(bm) x 16(bn) region of the 64x64 grid
    // -> per-XCD panel working set = 48 * 64 KiB = 3 MiB < 4 MiB L2. Bijective.
    const int g   = blockIdx.y * gridDim.x + blockIdx.x;
    const int xcd = g & 7;
    const int i   = g >> 3;
    const int bm  = (xcd >> 2) * 32 + (i >> 4);
    const int bn  = (xcd & 3) * 16 + (i & 15);

    const int wm = (wave & 1) * 64;
    const int wn = (wave >> 1) * 64;
    const int quad = lane >> 4;
    const int l15  = lane & 15;

    // acc[tj][ti] = transposed C/D: element r of acc[tj][ti] is
    //   out[bm*128+wm+ti*16+l15][bn*128+wn+tj*16+quad*4+r]
    floatx4 acc[4][4];
#pragma unroll
    for (int tj = 0; tj < 4; tj++)
#pragma unroll
        for (int ti = 0; ti < 4; ti++) acc[tj][ti] = (floatx4)0.0f;

    auto stage = [&](int buf, int k0) {
#pragma unroll
        for (int it = 0; it < 4; ++it) {
            int c   = it * 256 + tid;      // 16B chunk index 0..1023
            int row = c >> 3;              // tile row 0..127
            int kc  = c & 7;               // chunk-of-8-bf16 within BK=64
            int gkc = kc ^ (row & 7);      // XOR swizzle on the global side
            const unsigned short* gA = A + (size_t)(bm * 128 + row) * KDIM + k0 + gkc * 8;
            const unsigned short* gB = B + (size_t)(bn * 128 + row) * KDIM + k0 + gkc * 8;
            async16(gA, &As[buf][c * 8]);
            async16(gB, &Bs[buf][c * 8]);
        }
    };

    stage(0, 0);
    __syncthreads();                       // prologue drain

#pragma unroll
    for (int t = 0; t < 4; ++t) {
        if (t < 3) stage((t + 1) & 1, (t + 1) * 64);   // prefetch next K-tile
        const unsigned short* Ab = As[t & 1];
        const unsigned short* Bb = Bs[t & 1];
#pragma unroll
        for (int ks = 0; ks < 2; ++ks) {
            bf16x8 af[4], bfr[4];
            int kc = ks * 4 + quad;        // k = ks*32 + quad*8 -> chunk index
#pragma unroll
            for (int tt = 0; tt < 4; ++tt) {
                int m   = wm + tt * 16 + l15;
                int sA  = m * 8 + (kc ^ (m & 7));
                af[tt]  = *(const bf16x8*)&Ab[sA * 8];
                int n   = wn + tt * 16 + l15;
                int sB  = n * 8 + (kc ^ (n & 7));
                bfr[tt] = *(const bf16x8*)&Bb[sB * 8];
            }
            // swapped operands: D'[n][m] -> col(lane&15)=m, row(quad*4+r)=n
#pragma unroll
            for (int tj = 0; tj < 4; ++tj)
#pragma unroll
                for (int ti = 0; ti < 4; ++ti)
                    acc[tj][ti] = __builtin_amdgcn_mfma_f32_16x16x32_bf16(
                        bfr[tj], af[ti], acc[tj][ti], 0, 0, 0);
        }
        if (t < 3) __syncthreads();
    }

    // epilogue: per (ti,tj) one float4 store of 4 consecutive columns
    float variance = vraw[0] * vraw[0];
#pragma unroll
    for (int ti = 0; ti < 4; ++ti) {
        int row = bm * 128 + wm + ti * 16 + l15;
        float rav = ra[row];
        float* orow = out + (size_t)row * MCOLS;
#pragma unroll
        for (int tj = 0; tj < 4; ++tj) {
            int nbase = bn * 128 + wn + tj * 16 + quad * 4;
            floatx4 rbv = *(const floatx4*)&rb[nbase];
            floatx4 val;
#pragma unroll
            for (int r = 0; r < 4; ++r) {
                float s = rav + rbv[r] - 2.0f * acc[tj][ti][r];
                s = fmaxf(s, 0.0f);
                val[r] = variance * __expf(-0.5f * s);
            }
            *(floatx4*)&orow[nbase] = val;
        }
    }
}

extern "C" void kernel_launch(void* const* d_in, const int* in_sizes, int n_in,
                              void* d_out, int out_size, void* d_ws, size_t ws_size,
                              hipStream_t stream) {
    const float* x1   = (const float*)d_in[0];
    const float* x2   = (const float*)d_in[1];
    const float* araw = (const float*)d_in[2];
    const float* vraw = (const float*)d_in[3];
    float* out = (float*)d_out;

    char* ws = (char*)d_ws;
    float* sa = (float*)ws;                               // 256 f32   @ 0
    float* ra = (float*)(ws + 1024);                      // 8192 f32  @ 1 KiB
    float* rb = (float*)(ws + 1024 + 32768);              // 8192 f32
    unsigned short* Amat = (unsigned short*)(ws + 66560);                            // 4 MiB bf16
    unsigned short* Bmat = (unsigned short*)(ws + 66560 + (size_t)NROWS * KDIM * 2); // 4 MiB bf16

    prep_alpha<<<1, 256, 0, stream>>>(araw, sa);
    prep_rows<<<NROWS + MCOLS, 256, 0, stream>>>(x1, x2, sa, Amat, Bmat, ra, rb);

    dim3 grid(MCOLS / 128, NROWS / 128);
    rbf_gemm<<<grid, 256, 0, stream>>>(Amat, Bmat, ra, rb, vraw, out);
}

// Round 5
// 304.616 us; speedup vs baseline: 1.0374x; 1.0275x over previous
//
#include <hip/hip_runtime.h>
#include <stdint.h>

#define NROWS 8192
#define MCOLS 8192
#define KDIM  256

typedef __bf16 bf16x8 __attribute__((ext_vector_type(8)));
typedef float  floatx4 __attribute__((ext_vector_type(4)));
typedef unsigned short ushort4v __attribute__((ext_vector_type(4)));

__device__ __forceinline__ unsigned short f32_to_bf16_rne(float f) {
    unsigned int u = __float_as_uint(f);
    u += 0x7FFFu + ((u >> 16) & 1u);   // round-to-nearest-even
    return (unsigned short)(u >> 16);
}
__device__ __forceinline__ float bf16_to_f32(unsigned short h) {
    return __uint_as_float(((unsigned int)h) << 16);
}

// async 16B global -> LDS (wave-uniform base + lane*16 pattern required)
__device__ __forceinline__ void async16(const void* g, void* l) {
    __builtin_amdgcn_global_load_lds(
        (const __attribute__((address_space(1))) unsigned int*)g,
        (__attribute__((address_space(3))) unsigned int*)l,
        16, 0, 0);
}

// ---------------- kernel 1: alpha = softmax(alpha_raw^2), sa = sqrt(alpha) ----
__global__ void prep_alpha(const float* __restrict__ araw, float* __restrict__ sa) {
    int d = threadIdx.x;
    float z = araw[d];
    z = z * z;
    float m = z;
#pragma unroll
    for (int off = 32; off; off >>= 1) m = fmaxf(m, __shfl_xor(m, off));
    __shared__ float wred[4];
    if ((d & 63) == 0) wred[d >> 6] = m;
    __syncthreads();
    float mx = fmaxf(fmaxf(wred[0], wred[1]), fmaxf(wred[2], wred[3]));
    float e = __expf(z - mx);
    float s = e;
#pragma unroll
    for (int off = 32; off; off >>= 1) s += __shfl_xor(s, off);
    __syncthreads();
    if ((d & 63) == 0) wred[d >> 6] = s;
    __syncthreads();
    float sum = wred[0] + wred[1] + wred[2] + wred[3];
    sa[d] = sqrtf(e / sum);
}

// ---------------- kernel 2: scale rows by sa, round to bf16, norms from rounded
// v4: one row per WAVE, float4 per lane (16 B coalesced), shuffle-only reduce,
// no LDS, no barriers. 4096 blocks x 256 threads cover 16384 rows.
__global__ void prep_rows(const float* __restrict__ x1, const float* __restrict__ x2,
                          const float* __restrict__ sa,
                          unsigned short* __restrict__ Amat, unsigned short* __restrict__ Bmat,
                          float* __restrict__ ra, float* __restrict__ rb) {
    int wave = threadIdx.x >> 6;
    int lane = threadIdx.x & 63;
    int grow = blockIdx.x * 4 + wave;          // 0 .. 16383
    const float* x; unsigned short* mat; float* nrm; int row;
    if (grow < NROWS) { x = x1; mat = Amat; nrm = ra; row = grow; }
    else              { x = x2; mat = Bmat; nrm = rb; row = grow - NROWS; }

    floatx4 v  = *(const floatx4*)&x[(size_t)row * KDIM + lane * 4];
    floatx4 sv = *(const floatx4*)&sa[lane * 4];
    ushort4v h;
    float p = 0.0f;
#pragma unroll
    for (int j = 0; j < 4; ++j) {
        float f = v[j] * sv[j];
        unsigned short hh = f32_to_bf16_rne(f);
        h[j] = hh;
        float fv = bf16_to_f32(hh);
        p += fv * fv;
    }
    *(ushort4v*)&mat[(size_t)row * KDIM + lane * 4] = h;
#pragma unroll
    for (int off = 32; off; off >>= 1) p += __shfl_xor(p, off);
    if (lane == 0) nrm[row] = p;
}

// ---------------- kernel 3: NT-GEMM + fused RBF epilogue ---------------------
// C[i,j] = sum_k A[i,k]*B[j,k];  out = var*exp(-0.5*max(ra_i - 2C + rb_j, 0))
// Tile 128x128, BK=64, 4 waves (2x2), each wave 64x64 via 4x4 of 16x16x32 MFMA.
// v4 (resubmit; prior round was an infra failure, no measurement):
//   WRITE-BOUND kernel (write roofline 43 us; MFMA ~4 us). The lever is TLP:
//   - SINGLE-buffered 32 KiB LDS (v2/v3's 64 KiB dbuf halved blocks/CU to 2 and
//     regressed 128->141 us; m132 lesson). Restores 4-5 blocks/CU so one
//     block's store-drain overlaps other blocks' compute.
//   - kept from v3: transposed acc (mfma(b,a)) -> dwordx4 stores (16/thread),
//     XCD-slab swizzle, XOR LDS swizzle, plain stores (no NT).
//   - final barrier skipped (epilogue reads no LDS).
__global__ __launch_bounds__(256) void rbf_gemm(
    const unsigned short* __restrict__ A, const unsigned short* __restrict__ B,
    const float* __restrict__ ra, const float* __restrict__ rb,
    const float* __restrict__ vraw, float* __restrict__ out)
{
    __shared__ unsigned short As[128 * 64];   // 16 KiB
    __shared__ unsigned short Bs[128 * 64];   // 16 KiB

    const int tid  = threadIdx.x;
    const int lane = tid & 63;
    const int wave = tid >> 6;

    // XCD-slab swizzle: each XCD owns a 32(bm) x 16(bn) region of the 64x64 grid
    // -> per-XCD panel working set 3 MiB < 4 MiB L2. Bijective (4096 % 8 == 0).
    const int g   = blockIdx.y * gridDim.x + blockIdx.x;
    const int xcd = g & 7;
    const int i   = g >> 3;
    const int bm  = (xcd >> 2) * 32 + (i >> 4);
    const int bn  = (xcd & 3) * 16 + (i & 15);

    const int wm = (wave & 1) * 64;
    const int wn = (wave >> 1) * 64;
    const int quad = lane >> 4;
    const int l15  = lane & 15;

    // transposed C/D: element r of acc[tj][ti] is
    //   out[bm*128+wm+ti*16+l15][bn*128+wn+tj*16+quad*4+r]
    floatx4 acc[4][4];
#pragma unroll
    for (int tj = 0; tj < 4; tj++)
#pragma unroll
        for (int ti = 0; ti < 4; ti++) acc[tj][ti] = (floatx4)0.0f;

    for (int t = 0; t < 4; ++t) {
        int k0 = t * 64;
#pragma unroll
        for (int it = 0; it < 4; ++it) {
            int c   = it * 256 + tid;      // 16B chunk index 0..1023
            int row = c >> 3;              // tile row 0..127
            int kc  = c & 7;               // chunk-of-8-bf16 within BK=64
            int gkc = kc ^ (row & 7);      // XOR swizzle on the global side
            const unsigned short* gA = A + (size_t)(bm * 128 + row) * KDIM + k0 + gkc * 8;
            const unsigned short* gB = B + (size_t)(bn * 128 + row) * KDIM + k0 + gkc * 8;
            async16(gA, &As[c * 8]);
            async16(gB, &Bs[c * 8]);
        }
        __syncthreads();                   // stage resident

#pragma unroll
        for (int ks = 0; ks < 2; ++ks) {
            bf16x8 af[4], bfr[4];
            int kc = ks * 4 + quad;        // k = ks*32 + quad*8 -> chunk index
#pragma unroll
            for (int tt = 0; tt < 4; ++tt) {
                int m   = wm + tt * 16 + l15;
                int sA  = m * 8 + (kc ^ (m & 7));
                af[tt]  = *(const bf16x8*)&As[sA * 8];
                int n   = wn + tt * 16 + l15;
                int sB  = n * 8 + (kc ^ (n & 7));
                bfr[tt] = *(const bf16x8*)&Bs[sB * 8];
            }
            // swapped operands: D'[n][m] -> col(lane&15)=m, row(quad*4+r)=n
#pragma unroll
            for (int tj = 0; tj < 4; ++tj)
#pragma unroll
                for (int ti = 0; ti < 4; ++ti)
                    acc[tj][ti] = __builtin_amdgcn_mfma_f32_16x16x32_bf16(
                        bfr[tj], af[ti], acc[tj][ti], 0, 0, 0);
        }
        if (t < 3) __syncthreads();        // protect LDS before next stage
    }

    // epilogue: per (ti,tj) one float4 store of 4 consecutive columns
    float variance = vraw[0] * vraw[0];
#pragma unroll
    for (int ti = 0; ti < 4; ++ti) {
        int row = bm * 128 + wm + ti * 16 + l15;
        float rav = ra[row];
        float* orow = out + (size_t)row * MCOLS;
#pragma unroll
        for (int tj = 0; tj < 4; ++tj) {
            int nbase = bn * 128 + wn + tj * 16 + quad * 4;
            floatx4 rbv = *(const floatx4*)&rb[nbase];
            floatx4 val;
#pragma unroll
            for (int r = 0; r < 4; ++r) {
                float s = rav + rbv[r] - 2.0f * acc[tj][ti][r];
                s = fmaxf(s, 0.0f);
                val[r] = variance * __expf(-0.5f * s);
            }
            *(floatx4*)&orow[nbase] = val;
        }
    }
}

extern "C" void kernel_launch(void* const* d_in, const int* in_sizes, int n_in,
                              void* d_out, int out_size, void* d_ws, size_t ws_size,
                              hipStream_t stream) {
    const float* x1   = (const float*)d_in[0];
    const float* x2   = (const float*)d_in[1];
    const float* araw = (const float*)d_in[2];
    const float* vraw = (const float*)d_in[3];
    float* out = (float*)d_out;

    char* ws = (char*)d_ws;
    float* sa = (float*)ws;                               // 256 f32   @ 0
    float* ra = (float*)(ws + 1024);                      // 8192 f32  @ 1 KiB
    float* rb = (float*)(ws + 1024 + 32768);              // 8192 f32
    unsigned short* Amat = (unsigned short*)(ws + 66560);                            // 4 MiB bf16
    unsigned short* Bmat = (unsigned short*)(ws + 66560 + (size_t)NROWS * KDIM * 2); // 4 MiB bf16

    prep_alpha<<<1, 256, 0, stream>>>(araw, sa);
    prep_rows<<<(NROWS + MCOLS) / 4, 256, 0, stream>>>(x1, x2, sa, Amat, Bmat, ra, rb);

    dim3 grid(MCOLS / 128, NROWS / 128);
    rbf_gemm<<<grid, 256, 0, stream>>>(Amat, Bmat, ra, rb, vraw, out);
}